// Round 6
// baseline (316.994 us; speedup 1.0000x reference)
//
#include <hip/hip_runtime.h>
#include <math.h>

// ---------------------------------------------------------------------------
// TemporalGuidedModule round 6:
//  - gemm4_k: 64p x 256o, BK=32, 4 waves, padded-pitch LDS (72B rows), dbuf,
//    grid 512 = 2 blocks/CU. Template IHM reads X from head-major layout.
//  - value & msda_out in HEAD-MAJOR [B][H][P][32]: 64B rows -> patch-mapped
//    msda waves gather adjacent lines (4x fewer L1 transactions).
//  - msda: wave = 8x8 pixel patch, lanes = pixels, same (h,dh) per instr;
//    sa staged transposed in LDS; full 8pt x 4corner unroll (MLP).
// ---------------------------------------------------------------------------

#define PIX 16384
#define BATCH 2
#define CH 256

typedef short bf16x8 __attribute__((ext_vector_type(8)));
typedef float f32x4 __attribute__((ext_vector_type(4)));

__device__ __forceinline__ ushort f2bf(float f) {
  union { float f; unsigned u; } v; v.f = f;
  unsigned u = v.u;
  unsigned r = u + 0x7fffu + ((u >> 16) & 1u);   // RNE
  return (ushort)(r >> 16);
}
__device__ __forceinline__ float bfl(unsigned u) {
  union { unsigned u; float f; } v; v.u = u << 16; return v.f;
}
__device__ __forceinline__ float bfh(unsigned u) {
  union { unsigned u; float f; } v; v.u = u & 0xffff0000u; return v.f;
}
__device__ __forceinline__ unsigned fuse_u32(unsigned a, unsigned b, bool mul) {
  float rl = mul ? bfl(a) * bfl(b) : bfl(a) + bfl(b);
  float rh = mul ? bfh(a) * bfh(b) : bfh(a) + bfh(b);
  return (unsigned)f2bf(rl) | ((unsigned)f2bf(rh) << 16);
}

// --------------------------------------------------------------------------
// Weight prep + bias concat.
// --------------------------------------------------------------------------
__global__ __launch_bounds__(256) void wprep_k(
    const float* __restrict__ W_in1, const float* __restrict__ Wo,
    const float* __restrict__ Wt1, const float* __restrict__ Wt2,
    const float* __restrict__ Wout, const float* __restrict__ Ws,
    const float* __restrict__ Wa, const float* __restrict__ bs_off,
    const float* __restrict__ ba, ushort* __restrict__ wb,
    float* __restrict__ bsa)
{
  const int blk = blockIdx.x, k = threadIdx.x;
  if (blk >= 1472) {
    if (k < 128) bsa[k] = bs_off[k];
    else if (k < 192) bsa[k] = ba[k - 128];
    return;
  }
  const float* src;
  if (blk < 256) src = W_in1 + (size_t)blk * 256;
  else if (blk < 512) src = Wo + (size_t)(blk - 256) * 256;
  else if (blk < 768) src = Wt1 + (size_t)(blk - 512) * 256;
  else if (blk < 1024) src = Wt2 + (size_t)(blk - 768) * 256;
  else if (blk < 1280) src = Wout + (size_t)(blk - 1024) * 256;
  else if (blk < 1408) src = Ws + (size_t)(blk - 1280) * 256;
  else src = Wa + (size_t)(blk - 1408) * 256;
  wb[(size_t)blk * 256 + k] = f2bf(src[k]);
}

// Wv' = Wv @ W_in2 (bf16), bv' = Wv @ b_in2 + bv.
__global__ __launch_bounds__(256) void wvcomp_k(
    const float* __restrict__ Wv, const float* __restrict__ W_in2,
    const float* __restrict__ b_in2, const float* __restrict__ bv,
    ushort* __restrict__ Wvp, float* __restrict__ bvp)
{
  const int o = blockIdx.x, k = threadIdx.x;
  float acc = 0.f;
  #pragma unroll 8
  for (int c = 0; c < 256; ++c)
    acc += Wv[(size_t)o * 256 + c] * W_in2[(size_t)c * 256 + k];
  Wvp[(size_t)o * 256 + k] = f2bf(acc);
  __shared__ float red[256];
  red[k] = Wv[(size_t)o * 256 + k] * b_in2[k];
  __syncthreads();
  for (int s = 128; s > 0; s >>= 1) {
    if (k < s) red[k] += red[k + s];
    __syncthreads();
  }
  if (k == 0) bvp[o] = red[0] + bv[o];
}

// --------------------------------------------------------------------------
// Transpose-convert: [B][C][P] f32 -> [B][P][C] bf16.
// --------------------------------------------------------------------------
__global__ __launch_bounds__(256) void tconv_k(const float* __restrict__ in,
                                               ushort* __restrict__ out)
{
  __shared__ float t[32][33];
  const int tid = threadIdx.x;
  const int b = blockIdx.z;
  const int p0 = blockIdx.x * 32, c0 = blockIdx.y * 32;
  const int tx = tid & 31, ty = tid >> 5;
  const float* inb = in + (size_t)b * CH * PIX;
  #pragma unroll
  for (int i = 0; i < 4; ++i)
    t[ty + i * 8][tx] = inb[(size_t)(c0 + ty + i * 8) * PIX + p0 + tx];
  __syncthreads();
  const int cx = (tid & 15) * 2, py = tid >> 4;
  ushort* outb = out + (size_t)b * PIX * CH;
  #pragma unroll
  for (int i = 0; i < 2; ++i) {
    int pl = py + i * 16;
    unsigned lo = f2bf(t[cx][pl]);
    unsigned hi = f2bf(t[cx + 1][pl]);
    *(unsigned*)(outb + (size_t)(p0 + pl) * CH + c0 + cx) = lo | (hi << 16);
  }
}

// --------------------------------------------------------------------------
// gemm4_k: Out[p][o] = sum_k X[p][k]*W[o][k] + bias[o], Cout=256, Cin=256.
// Tile 64p x 256o, BK=32, 256 thr / 4 waves (2x2), wave tile 32p x 128o.
// Padded LDS: rows 64B data + 8B pad (pitch 72B). Dbuf. Grid 512 = 2/CU.
// IHM: X in head-major [H][P][32] (k0 32-aligned -> one plane per K-step).
// OMODE 0: pm bf16 [P][256]; 1: cm f32 direct; 3: head-major bf16 [H][P][32].
// FUSE 0 none; 1 x*=in2; 2 x+=in2 (in2 pm bf16).
// --------------------------------------------------------------------------
template<int FUSE, bool RELU, int OMODE, bool IHM>
__global__ __launch_bounds__(256, 2) void gemm4_k(
    const ushort* __restrict__ in, const ushort* __restrict__ in2,
    const ushort* __restrict__ Wb, const float* __restrict__ bias,
    void* __restrict__ out)
{
  __shared__ __align__(16) char smem[46080];   // X dbuf 2x4608 | W dbuf 2x18432
  const int tid = threadIdx.x;
  const int b = blockIdx.z;
  const int p0 = blockIdx.x * 64;

  const ushort* inb = in + (size_t)b * PIX * CH;

  // X staging: 4 thr/row (row=tid>>2, group g=tid&3, 16B each)
  const int xrw = tid >> 2, xg = tid & 3;
  const ushort* xsrc_pm = inb + (size_t)(p0 + xrw) * CH + xg * 8;   // + kb
  const ushort* xsrc_hm = inb + (size_t)(p0 + xrw) * 32 + xg * 8;   // + (kb>>5)*PIX*32
  const ushort* x2src = (FUSE != 0)
      ? in2 + (size_t)b * PIX * CH + (size_t)(p0 + xrw) * CH + xg * 8
      : (const ushort*)nullptr;
  // W staging: 1 thr/row, 64B each
  const ushort* wsrc = Wb + (size_t)tid * CH;

  const int l = tid & 63, wid = tid >> 6;
  const int wm = wid >> 1, wn = wid & 1;
  const int lr = l & 15, g4 = l >> 4;

  f32x4 acc[2][8];
  #pragma unroll
  for (int i = 0; i < 2; ++i)
    #pragma unroll
    for (int j = 0; j < 8; ++j) acc[i][j] = (f32x4){0.f, 0.f, 0.f, 0.f};

  uint4 xr, x2r, wr[4];

#define LOADT(kb)                                                              \
  {                                                                            \
    if (IHM) xr = *(const uint4*)(xsrc_hm + (size_t)((kb) >> 5) * PIX * 32);   \
    else     xr = *(const uint4*)(xsrc_pm + (kb));                             \
    if (FUSE != 0) x2r = *(const uint4*)(x2src + (kb));                        \
    _Pragma("unroll")                                                          \
    for (int j = 0; j < 4; ++j) wr[j] = *(const uint4*)(wsrc + (kb) + j * 8);  \
  }

#define WRITET(buf)                                                            \
  {                                                                            \
    uint4 v = xr;                                                              \
    if (FUSE != 0) {                                                           \
      unsigned* pa = (unsigned*)&v;                                            \
      const unsigned* pb = (const unsigned*)&x2r;                              \
      _Pragma("unroll")                                                        \
      for (int w = 0; w < 4; ++w) pa[w] = fuse_u32(pa[w], pb[w], FUSE == 1);   \
    }                                                                          \
    *(uint4*)(smem + (buf) * 4608 + xrw * 72 + xg * 16) = v;                   \
    char* wbp = smem + 9216 + (buf) * 18432 + tid * 72;                        \
    _Pragma("unroll")                                                          \
    for (int j = 0; j < 4; ++j) *(uint4*)(wbp + j * 16) = wr[j];               \
  }

  LOADT(0)
  WRITET(0)
  __syncthreads();

  for (int t = 0; t < 8; ++t) {
    if (t < 7) LOADT((t + 1) * 32)
    const char* XB = smem + (t & 1) * 4608;
    const char* WB = smem + 9216 + (t & 1) * 18432;
    bf16x8 af[2], bfr[8];
    #pragma unroll
    for (int fm = 0; fm < 2; ++fm)
      af[fm] = *(const bf16x8*)(XB + (wm * 32 + fm * 16 + lr) * 72 + g4 * 16);
    #pragma unroll
    for (int fn = 0; fn < 8; ++fn)
      bfr[fn] = *(const bf16x8*)(WB + (wn * 128 + fn * 16 + lr) * 72 + g4 * 16);
    #pragma unroll
    for (int fm = 0; fm < 2; ++fm)
      #pragma unroll
      for (int fn = 0; fn < 8; ++fn)
        acc[fm][fn] = __builtin_amdgcn_mfma_f32_16x16x32_bf16(af[fm], bfr[fn], acc[fm][fn], 0, 0, 0);
    if (t < 7) WRITET((t + 1) & 1)
    __syncthreads();
  }
#undef LOADT
#undef WRITET

  // ---- epilogue ---- C/D: col(o) = lr, row(p) = g4*4 + reg
  float bvv[8];
  #pragma unroll
  for (int fn = 0; fn < 8; ++fn) bvv[fn] = bias[wn * 128 + fn * 16 + lr];

  if (OMODE == 1) {               // cm f32 direct (final output)
    float* outb = (float*)out + (size_t)b * CH * PIX;
    #pragma unroll
    for (int fm = 0; fm < 2; ++fm)
      #pragma unroll
      for (int fn = 0; fn < 8; ++fn) {
        float4 v;
        v.x = acc[fm][fn][0] + bvv[fn]; v.y = acc[fm][fn][1] + bvv[fn];
        v.z = acc[fm][fn][2] + bvv[fn]; v.w = acc[fm][fn][3] + bvv[fn];
        if (RELU) {
          v.x = fmaxf(v.x, 0.f); v.y = fmaxf(v.y, 0.f);
          v.z = fmaxf(v.z, 0.f); v.w = fmaxf(v.w, 0.f);
        }
        *(float4*)(outb + (size_t)(wn * 128 + fn * 16 + lr) * PIX + p0 + wm * 32 + fm * 16 + g4 * 4) = v;
      }
  } else {                        // bf16 via LDS bounce [64][264] halves
    ushort* El = (ushort*)smem;
    #pragma unroll
    for (int fm = 0; fm < 2; ++fm)
      #pragma unroll
      for (int fn = 0; fn < 8; ++fn)
        #pragma unroll
        for (int r = 0; r < 4; ++r) {
          const int p = wm * 32 + fm * 16 + g4 * 4 + r;
          float v = acc[fm][fn][r] + bvv[fn];
          if (RELU) v = fmaxf(v, 0.f);
          El[p * 264 + wn * 128 + fn * 16 + lr] = f2bf(v);
        }
    __syncthreads();
    ushort* outb = (ushort*)out + (size_t)b * PIX * CH;
    const int row = tid >> 2, seg = tid & 3;
    if (OMODE == 0) {             // pixel-major [P][256]
      #pragma unroll
      for (int j = 0; j < 8; ++j) {
        uint4 v = *(uint4*)(smem + row * 528 + seg * 128 + j * 16);
        *(uint4*)(outb + (size_t)(p0 + row) * CH + seg * 64 + j * 8) = v;
      }
    } else {                      // OMODE 3: head-major [H][P][32]
      #pragma unroll
      for (int j = 0; j < 8; ++j) {
        uint4 v = *(uint4*)(smem + row * 528 + seg * 128 + j * 16);
        const int o = seg * 64 + j * 8;
        *(uint4*)(outb + ((size_t)(o >> 5) * PIX + p0 + row) * 32 + (o & 31)) = v;
      }
    }
  }
}

// --------------------------------------------------------------------------
// gemm2_k — retained for the Cout=192 offs+attn GEMM (pm f32 out).
// --------------------------------------------------------------------------
template<int FUSE, bool RELU, int OMODE>
__global__ __launch_bounds__(256, 3) void gemm2_k(
    const ushort* __restrict__ in, const ushort* __restrict__ in2,
    const ushort* __restrict__ Wb, const float* __restrict__ bias,
    void* __restrict__ out, int ldo, size_t obstride)
{
  __shared__ __align__(16) char smem[49152];
  const int tid = threadIdx.x;
  const int b = blockIdx.z;
  const int p0 = blockIdx.x * 128;
  const int o0 = blockIdx.y * 64;

  const ushort* inb = in + (size_t)b * PIX * CH;

  const int spr = tid >> 1, skh = tid & 1;
  const ushort* xsrc = inb + (size_t)(p0 + spr) * CH + skh * 32;
  const int xrow = spr * 128, xsw = spr & 7;
  const int swr = tid >> 2, swq = tid & 3;
  const ushort* wsrc = Wb + (size_t)(o0 + swr) * CH + swq * 16;
  const int wrow = swr * 128, wsw = swr & 7;

  const int l = tid & 63, wv = tid >> 6;
  const int lr = l & 15, g4 = l >> 4;

  f32x4 acc[2][4];
  #pragma unroll
  for (int i = 0; i < 2; ++i)
    #pragma unroll
    for (int j = 0; j < 4; ++j) acc[i][j] = (f32x4){0.f, 0.f, 0.f, 0.f};

  uint4 xr[4], wr[2];

#define LOADT(kb)                                                              \
  {                                                                            \
    _Pragma("unroll")                                                          \
    for (int j = 0; j < 4; ++j) xr[j] = *(const uint4*)(xsrc + (kb) + j * 8);  \
    _Pragma("unroll")                                                          \
    for (int j = 0; j < 2; ++j) wr[j] = *(const uint4*)(wsrc + (kb) + j * 8);  \
  }

#define WRITET(buf)                                                            \
  {                                                                            \
    char* xb = smem + (buf) * 16384 + xrow;                                    \
    _Pragma("unroll")                                                          \
    for (int j = 0; j < 4; ++j)                                                \
      *(uint4*)(xb + (((skh * 4 + j) ^ xsw) * 16)) = xr[j];                    \
    char* wbp = smem + 32768 + (buf) * 8192 + wrow;                            \
    _Pragma("unroll")                                                          \
    for (int j = 0; j < 2; ++j)                                                \
      *(uint4*)(wbp + (((swq * 2 + j) ^ wsw) * 16)) = wr[j];                   \
  }

  LOADT(0)
  WRITET(0)
  __syncthreads();

  for (int t = 0; t < 4; ++t) {
    if (t < 3) LOADT((t + 1) * 64)
    const char* XB = smem + (t & 1) * 16384;
    const char* WB = smem + 32768 + (t & 1) * 8192;
    bf16x8 af[2][2], bfr[4][2];
    #pragma unroll
    for (int fm = 0; fm < 2; ++fm) {
      const int p = wv * 32 + fm * 16 + lr;
      #pragma unroll
      for (int kh = 0; kh < 2; ++kh)
        af[fm][kh] = *(const bf16x8*)(XB + p * 128 + (((kh * 4 + g4) ^ (p & 7)) * 16));
    }
    #pragma unroll
    for (int fn = 0; fn < 4; ++fn) {
      const int o = fn * 16 + lr;
      #pragma unroll
      for (int kh = 0; kh < 2; ++kh)
        bfr[fn][kh] = *(const bf16x8*)(WB + o * 128 + (((kh * 4 + g4) ^ (o & 7)) * 16));
    }
    #pragma unroll
    for (int fm = 0; fm < 2; ++fm)
      #pragma unroll
      for (int fn = 0; fn < 4; ++fn) {
        acc[fm][fn] = __builtin_amdgcn_mfma_f32_16x16x32_bf16(af[fm][0], bfr[fn][0], acc[fm][fn], 0, 0, 0);
        acc[fm][fn] = __builtin_amdgcn_mfma_f32_16x16x32_bf16(af[fm][1], bfr[fn][1], acc[fm][fn], 0, 0, 0);
      }
    if (t < 3) WRITET((t + 1) & 1)
    __syncthreads();
  }
#undef LOADT
#undef WRITET

  float bvv[4];
  #pragma unroll
  for (int fn = 0; fn < 4; ++fn) bvv[fn] = bias[o0 + fn * 16 + lr];

  {                               // pm f32 via LDS bounce
    float* El = (float*)smem;     // [128][68] f32
    #pragma unroll
    for (int fm = 0; fm < 2; ++fm)
      #pragma unroll
      for (int fn = 0; fn < 4; ++fn)
        #pragma unroll
        for (int r = 0; r < 4; ++r) {
          const int p = wv * 32 + fm * 16 + g4 * 4 + r;
          El[p * 68 + fn * 16 + lr] = acc[fm][fn][r] + bvv[fn];
        }
    __syncthreads();
    float* outb = (float*)out + (size_t)b * obstride;
    const int row = tid >> 1, hh = tid & 1;
    #pragma unroll
    for (int j = 0; j < 8; ++j) {
      float4 v = *(float4*)(smem + row * 272 + hh * 128 + j * 16);
      *(float4*)(outb + (size_t)(p0 + row) * ldo + o0 + hh * 32 + j * 4) = v;
    }
  }
}

// --------------------------------------------------------------------------
// msda: block = 8x8 pixel patch. Waves: lane = pixel, wave q handles slots
// (h,dh) = q, q+4, q+8, q+12. value/out HEAD-MAJOR [B][H][P][32].
// sa [B*P][192] staged transposed in LDS (S[comp][pixel], pitch 66).
// --------------------------------------------------------------------------
__global__ __launch_bounds__(256, 2) void msda_k(
    const ushort* __restrict__ value, const float* __restrict__ sa,
    ushort* __restrict__ out)
{
  __shared__ float S[192 * 66];
  const int tid = threadIdx.x;
  const int patch = blockIdx.x;
  const int b = blockIdx.z;
  const int pay = (patch >> 4) * 8, pax = (patch & 15) * 8;

  // ---- stage sa transposed ----
  {
    const int pr = tid >> 2, cc = tid & 3;
    const int pp = (pay + (pr >> 3)) * 128 + pax + (pr & 7);
    const float* srow = sa + ((size_t)b * PIX + pp) * 192 + cc * 4;
    #pragma unroll
    for (int it = 0; it < 12; ++it) {
      float4 v = *(const float4*)(srow + it * 16);
      const int c = cc * 4 + it * 16;
      S[(c + 0) * 66 + pr] = v.x;
      S[(c + 1) * 66 + pr] = v.y;
      S[(c + 2) * 66 + pr] = v.z;
      S[(c + 3) * 66 + pr] = v.w;
    }
  }
  __syncthreads();

  const int lane = tid & 63, q = tid >> 6;
  const int px = pax + (lane & 7), py = pay + (lane >> 3);
  const int p = py * 128 + px;
  const ushort* vb = value + (size_t)b * PIX * CH;
  ushort* ob = out + (size_t)b * PIX * CH;

  #pragma unroll
  for (int s = 0; s < 4; ++s) {
    const int slot = s * 4 + q;
    const int h = slot >> 1, dh = slot & 1;

    float lg[8];
    float m = -1e30f;
    #pragma unroll
    for (int i = 0; i < 8; ++i) {
      lg[i] = S[(128 + h * 8 + i) * 66 + lane];
      m = fmaxf(m, lg[i]);
    }
    float sum = 0.f;
    #pragma unroll
    for (int i = 0; i < 8; ++i) { lg[i] = __expf(lg[i] - m); sum += lg[i]; }
    const float inv = 1.f / sum;

    const ushort* vh = vb + (size_t)h * PIX * 32 + dh * 16;

    float acc[16];
    #pragma unroll
    for (int i = 0; i < 16; ++i) acc[i] = 0.f;

    #pragma unroll
    for (int pt = 0; pt < 8; ++pt) {
      const float ox = S[(h * 16 + pt * 2) * 66 + lane];
      const float oy = S[(h * 16 + pt * 2 + 1) * 66 + lane];
      const float aw = lg[pt] * inv;
      const float ix = px + ox, iy = py + oy;   // grid_sample -0.5 cancels
      const float xf = floorf(ix), yf = floorf(iy);
      const float fx = ix - xf, fy = iy - yf;
      const int x0 = (int)xf, y0 = (int)yf;
      #pragma unroll
      for (int cr = 0; cr < 4; ++cr) {
        const int dx = cr & 1, dy = cr >> 1;
        const int xx = x0 + dx, yy = y0 + dy;
        const float wx = dx ? fx : (1.f - fx);
        const float wy = dy ? fy : (1.f - fy);
        const bool valid = ((unsigned)xx < 128u) & ((unsigned)yy < 128u);
        float w = valid ? (wx * wy * aw) : 0.f;
        const int xc = min(max(xx, 0), 127), yc = min(max(yy, 0), 127);
        const ushort* vr = vh + (size_t)(yc * 128 + xc) * 32;
        uint4 q0 = *(const uint4*)vr;
        uint4 q1 = *(const uint4*)(vr + 8);
        const unsigned* qw0 = (const unsigned*)&q0;
        const unsigned* qw1 = (const unsigned*)&q1;
        #pragma unroll
        for (int ww = 0; ww < 4; ++ww) {
          acc[2 * ww + 0] = fmaf(w, bfl(qw0[ww]), acc[2 * ww + 0]);
          acc[2 * ww + 1] = fmaf(w, bfh(qw0[ww]), acc[2 * ww + 1]);
          acc[8 + 2 * ww + 0] = fmaf(w, bfl(qw1[ww]), acc[8 + 2 * ww + 0]);
          acc[8 + 2 * ww + 1] = fmaf(w, bfh(qw1[ww]), acc[8 + 2 * ww + 1]);
        }
      }
    }
    unsigned r[8];
    #pragma unroll
    for (int k = 0; k < 8; ++k)
      r[k] = (unsigned)f2bf(acc[2 * k]) | ((unsigned)f2bf(acc[2 * k + 1]) << 16);
    ushort* dst = ob + ((size_t)h * PIX + p) * 32 + dh * 16;
    *(uint4*)dst = *(uint4*)&r[0];
    *(uint4*)(dst + 8) = *(uint4*)&r[4];
  }
}

extern "C" void kernel_launch(void* const* d_in, const int* in_sizes, int n_in,
                              void* d_out, int out_size, void* d_ws, size_t ws_size,
                              hipStream_t stream)
{
  const float* xt     = (const float*)d_in[0];
  const float* xt_1   = (const float*)d_in[1];
  const float* W_in1  = (const float*)d_in[2];
  const float* b_in1  = (const float*)d_in[3];
  const float* W_in2  = (const float*)d_in[4];
  const float* b_in2  = (const float*)d_in[5];
  const float* Wv     = (const float*)d_in[6];
  const float* bv     = (const float*)d_in[7];
  const float* Ws     = (const float*)d_in[8];
  const float* bs_off = (const float*)d_in[9];
  const float* Wa     = (const float*)d_in[10];
  const float* ba     = (const float*)d_in[11];
  const float* Wo     = (const float*)d_in[12];
  const float* bo     = (const float*)d_in[13];
  const float* Wt1    = (const float*)d_in[14];
  const float* bt1    = (const float*)d_in[15];
  const float* Wt2    = (const float*)d_in[16];
  const float* bt2    = (const float*)d_in[17];
  const float* Wout   = (const float*)d_in[18];
  const float* bout   = (const float*)d_in[19];

  char* ws = (char*)d_ws;
  const size_t SLOT = (size_t)BATCH * PIX * CH * 2;          // 16.78 MB
  const size_t SAB  = (size_t)BATCH * PIX * 192 * 4;         // 25.17 MB
  ushort* s0 = (ushort*)(ws + 0 * SLOT);   // xt_pm  -> xt_star(pm)
  ushort* s1 = (ushort*)(ws + 1 * SLOT);   // xt1_pm -> h1(pm)
  ushort* s2 = (ushort*)(ws + 2 * SLOT);   // x1 (pm, live)
  ushort* s3 = (ushort*)(ws + 3 * SLOT);   // value(hm) -> tg(pm)
  ushort* s4 = (ushort*)(ws + 4 * SLOT);   // msda_out(hm)
  float*  sa = (float*)(ws + 5 * SLOT);    // [B][P][192] offs+attn
  char* wbase = ws + 5 * SLOT + SAB;
  ushort* wb  = (ushort*)wbase;            // 1472x256 bf16
  ushort* wvp = (ushort*)(wbase + (size_t)1472 * 256 * 2);   // 256x256 bf16
  float* bsa  = (float*)(wbase + (size_t)1472 * 256 * 2 + (size_t)256 * 256 * 2);
  float* bvp  = bsa + 192;

  ushort* wb_in1 = wb;
  ushort* wb_o   = wb + 65536;
  ushort* wb_t1  = wb + 131072;
  ushort* wb_t2  = wb + 196608;
  ushort* wb_out = wb + 262144;
  ushort* wb_sa  = wb + 327680;            // 192 rows: Ws then Wa

  dim3 blk(256);
  dim3 gT(PIX / 32, CH / 32, BATCH);
  dim3 g4(PIX / 64, 1, BATCH);             // gemm4: 512 blocks
  dim3 gS(PIX / 128, 3, BATCH);            // gemm2 Cout=192
  dim3 gM(256, 1, BATCH);                  // msda: patches

  wprep_k<<<1473, blk, 0, stream>>>(W_in1, Wo, Wt1, Wt2, Wout, Ws, Wa, bs_off, ba, wb, bsa);
  wvcomp_k<<<256, blk, 0, stream>>>(Wv, W_in2, b_in2, bv, wvp, bvp);
  tconv_k<<<gT, blk, 0, stream>>>(xt, s0);
  tconv_k<<<gT, blk, 0, stream>>>(xt_1, s1);

  gemm4_k<0, false, 0, false><<<g4, blk, 0, stream>>>(s0, nullptr, wb_in1, b_in1, s2);  // x1 (pm)
  gemm4_k<0, false, 3, false><<<g4, blk, 0, stream>>>(s1, nullptr, wvp, bvp, s3);       // value (hm)
  gemm2_k<0, false, 2><<<gS, blk, 0, stream>>>(s2, nullptr, wb_sa, bsa, sa, 192, (size_t)PIX * 192);
  msda_k<<<gM, blk, 0, stream>>>(s3, sa, s4);                                           // msda (hm)
  gemm4_k<0, false, 0, true ><<<g4, blk, 0, stream>>>(s4, nullptr, wb_o, bo, s0);       // xt_star (pm)
  gemm4_k<1, true , 0, false><<<g4, blk, 0, stream>>>(s0, s2, wb_t1, bt1, s1);          // h1
  gemm4_k<0, false, 0, false><<<g4, blk, 0, stream>>>(s1, nullptr, wb_t2, bt2, s3);     // tg
  gemm4_k<2, true , 1, false><<<g4, blk, 0, stream>>>(s3, s2, wb_out, bout, d_out);     // out
}